// Round 6
// baseline (206.705 us; speedup 1.0000x reference)
//
#include <hip/hip_runtime.h>
#include <cstdint>

#define NODES 50000
#define FIN   128
#define C1    128   // HEADS*HID
#define HEADS 4
#define HID   32
#define CLS   40
#define SLOPE 0.2f

#define NBUCK ((NODES + 255) >> 8)   // 196
#define EPB 2048                     // edges per bucketA block
#define BCAP 8192                    // fixed bucket capacity (max actual ~4.3k)

__device__ __forceinline__ float lrelu(float v) { return v > 0.f ? v : SLOPE * v; }

__device__ __forceinline__ unsigned short f2bf(float f) {
    union { float f; unsigned u; } v; v.f = f;
    unsigned u = v.u;
    return (unsigned short)((u + 0x7FFFu + ((u >> 16) & 1u)) >> 16);
}
__device__ __forceinline__ float bf2f(unsigned short b) {
    union { unsigned u; float f; } v; v.u = ((unsigned)b) << 16;
    return v.f;
}
__device__ __forceinline__ float bflo(unsigned u) {
    union { unsigned x; float f; } v; v.x = u << 16; return v.f;
}
__device__ __forceinline__ float bfhi(unsigned u) {
    union { unsigned x; float f; } v; v.x = u & 0xffff0000u; return v.f;
}
// HW packed f32->bf16 (RNE): lo16=bf16(a), hi16=bf16(b)
__device__ __forceinline__ unsigned cvtpk(float a, float b) {
    unsigned r;
    asm("v_cvt_pk_bf16_f32 %0, %1, %2" : "=v"(r) : "v"(a), "v"(b));
    return r;
}

typedef __attribute__((ext_vector_type(8))) short bf16x8;
typedef __attribute__((ext_vector_type(4))) float f32x4;
typedef __attribute__((ext_vector_type(4), aligned(4))) int int4a;
typedef __attribute__((ext_vector_type(2), aligned(4))) int int2a;
typedef __attribute__((ext_vector_type(4), aligned(4))) float f32x4a;
typedef __attribute__((ext_vector_type(2), aligned(4))) float f32x2a;

// accumulate one edge's 16B chunk (8 bf16 channels) with weight w
__device__ __forceinline__ void acc8(float w, uint4 p, float* ac) {
    ac[0] = fmaf(w, bflo(p.x), ac[0]); ac[1] = fmaf(w, bfhi(p.x), ac[1]);
    ac[2] = fmaf(w, bflo(p.y), ac[2]); ac[3] = fmaf(w, bfhi(p.y), ac[3]);
    ac[4] = fmaf(w, bflo(p.z), ac[4]); ac[5] = fmaf(w, bfhi(p.z), ac[5]);
    ac[6] = fmaf(w, bflo(p.w), ac[6]); ac[7] = fmaf(w, bfhi(p.w), ac[7]);
}

// ---- prep: 9 blocks. b<8: W1 16-row transpose slice -> w1t bf16.
//      b==8: W2 -> w2t bf16 transposed + bwp init. ----
__global__ __launch_bounds__(256) void k_prep(const float* __restrict__ W1,
                                              const float* __restrict__ W2,
                                              unsigned short* __restrict__ w1t,
                                              unsigned short* __restrict__ w2t,
                                              int* __restrict__ bwp) {
    const int b = blockIdx.x, t = threadIdx.x;
    if (b < 8) {
        __shared__ unsigned short Tb[16][136];
        const int n0 = b * 16;
        const int k = t & 127, g = t >> 7;
#pragma unroll
        for (int i = 0; i < 8; i++)
            Tb[g * 8 + i][k] = f2bf(W1[(size_t)k * C1 + n0 + g * 8 + i]);
        __syncthreads();
        {
            int nl = t >> 4, k8 = (t & 15) * 8;
            *(uint4*)(w1t + (n0 + nl) * 128 + k8) = *(uint4*)(&Tb[nl][k8]);
        }
    } else {
        for (int p = t; p < CLS * 128; p += 256) {
            int n = p >> 7, k = p & 127;
            w2t[n * 128 + k] = f2bf(W2[(size_t)k * CLS + n]);
        }
        if (t < NBUCK) bwp[t] = t * BCAP;
    }
}

// ---- front: blocks [0,GB1) = GEMM1 (MFMA bf16 + fused att1);
//             blocks [GB1,..) = bucketA (independent inputs/outputs) ----
__global__ __launch_bounds__(256) void k_front(const float* __restrict__ X,
                                               const unsigned short* __restrict__ w1t,
                                               const float* __restrict__ AS,
                                               const float* __restrict__ AD,
                                               unsigned short* __restrict__ h1b,
                                               float* __restrict__ as1,
                                               float* __restrict__ ad1,
                                               const int* __restrict__ src,
                                               const int* __restrict__ dst, int E,
                                               int* __restrict__ bwp,
                                               int* __restrict__ tmp, int GB1) {
    __shared__ unsigned short Asm[64][136];
    __shared__ unsigned short Wt[128][136];
    __shared__ int cnt[NBUCK];
    __shared__ int bbs[NBUCK];
    const int t = threadIdx.x;

    if (blockIdx.x >= GB1) {
        // ---------------- bucketA body ----------------
        for (int i = t; i < NBUCK; i += 256) cnt[i] = 0;
        __syncthreads();
        const int e0 = (blockIdx.x - GB1) * EPB;
        int v[8], rb[8];
#pragma unroll
        for (int k = 0; k < 8; k++) {
            int e = e0 + k * 256 + t;
            rb[k] = -1;
            if (e < E) {
                int d = dst[e], s = src[e];
                int b = d >> 8;
                int r = atomicAdd(&cnt[b], 1);
                v[k] = (s << 8) | (d & 255);
                rb[k] = (r << 8) | b;
            }
        }
        __syncthreads();
        for (int i = t; i < NBUCK; i += 256) {
            int c = cnt[i];
            bbs[i] = c ? atomicAdd(&bwp[i], c) : 0;
        }
        __syncthreads();
#pragma unroll
        for (int k = 0; k < 8; k++) {
            if (rb[k] >= 0) {
                int b = rb[k] & 255;
                int r = rb[k] >> 8;
                tmp[bbs[b] + r] = v[k];
            }
        }
        return;
    }

    // ---------------- GEMM1 body ----------------
    const int row0 = blockIdx.x * 64;
#pragma unroll
    for (int i = 0; i < 8; i++) {
        int p = i * 256 + t;
        int n = p >> 4, k8 = (p & 15) * 8;
        *(uint4*)(&Wt[n][k8]) = *(const uint4*)(w1t + n * 128 + k8);
    }
    {
        int r = t >> 2, c0 = (t & 3) * 32;
        int gr = row0 + r;
        if (gr < NODES) {
#pragma unroll
            for (int i = 0; i < 4; i++) {
                float4 va = *(const float4*)(X + (size_t)gr * FIN + c0 + i * 8);
                float4 vb = *(const float4*)(X + (size_t)gr * FIN + c0 + i * 8 + 4);
                uint4 pk;
                pk.x = cvtpk(va.x, va.y);
                pk.y = cvtpk(va.z, va.w);
                pk.z = cvtpk(vb.x, vb.y);
                pk.w = cvtpk(vb.z, vb.w);
                *(uint4*)(&Asm[r][c0 + i * 8]) = pk;
            }
        } else {
            uint4 z = make_uint4(0, 0, 0, 0);
#pragma unroll
            for (int i = 0; i < 4; i++) *(uint4*)(&Asm[r][c0 + i * 8]) = z;
        }
    }
    __syncthreads();

    const int w = t >> 6, l = t & 63;
    const int lm = l & 15, quad = l >> 4;
    f32x4 acc[8];
#pragma unroll
    for (int ct = 0; ct < 8; ct++) acc[ct] = (f32x4){0.f, 0.f, 0.f, 0.f};
#pragma unroll
    for (int kt = 0; kt < 4; kt++) {
        bf16x8 a = *(const bf16x8*)(&Asm[w * 16 + lm][kt * 32 + quad * 8]);
#pragma unroll
        for (int ct = 0; ct < 8; ct++) {
            bf16x8 b = *(const bf16x8*)(&Wt[ct * 16 + lm][kt * 32 + quad * 8]);
            acc[ct] = __builtin_amdgcn_mfma_f32_16x16x32_bf16(a, b, acc[ct], 0, 0, 0);
        }
    }
    __syncthreads();
#pragma unroll
    for (int ct = 0; ct < 8; ct++)
#pragma unroll
        for (int r = 0; r < 4; r++)
            Asm[w * 16 + quad * 4 + r][ct * 16 + lm] = f2bf(acc[ct][r]);
    __syncthreads();
    {
        int r = t >> 2, c0 = (t & 3) * 32;
        int gr = row0 + r;
        if (gr < NODES) {
#pragma unroll
            for (int i = 0; i < 4; i++)
                *(uint4*)(h1b + (size_t)gr * C1 + c0 + i * 8) =
                    *(uint4*)(&Asm[r][c0 + i * 8]);
        }
    }
    {
        // att1: vectorized LDS reads (uint4) + float4 AS/AD loads
        int r = t >> 2, h = t & 3;
        int gr = row0 + r;
        if (gr < NODES) {
            float s = 0.f, d = 0.f;
#pragma unroll
            for (int i = 0; i < 4; i++) {
                uint4 hv = *(const uint4*)(&Asm[r][h * 32 + i * 8]);
                float4 a0 = *(const float4*)(AS + h * HID + i * 8);
                float4 a1 = *(const float4*)(AS + h * HID + i * 8 + 4);
                float4 d0 = *(const float4*)(AD + h * HID + i * 8);
                float4 d1 = *(const float4*)(AD + h * HID + i * 8 + 4);
                float v0 = bflo(hv.x), v1 = bfhi(hv.x), v2 = bflo(hv.y), v3 = bfhi(hv.y);
                float v4 = bflo(hv.z), v5 = bfhi(hv.z), v6 = bflo(hv.w), v7 = bfhi(hv.w);
                s = fmaf(v0, a0.x, s); s = fmaf(v1, a0.y, s);
                s = fmaf(v2, a0.z, s); s = fmaf(v3, a0.w, s);
                s = fmaf(v4, a1.x, s); s = fmaf(v5, a1.y, s);
                s = fmaf(v6, a1.z, s); s = fmaf(v7, a1.w, s);
                d = fmaf(v0, d0.x, d); d = fmaf(v1, d0.y, d);
                d = fmaf(v2, d0.z, d); d = fmaf(v3, d0.w, d);
                d = fmaf(v4, d1.x, d); d = fmaf(v5, d1.y, d);
                d = fmaf(v6, d1.z, d); d = fmaf(v7, d1.w, d);
            }
            as1[gr * HEADS + h] = s;
            ad1[gr * HEADS + h] = d;
        }
    }
}

// ---- pass B: per-bucket degree+scan -> rowptr/deg, scatter col + dloc +
//      PRECOMPUTED layer-1 edge weights (4 heads, f32). ad1 for the bucket's
//      256 nodes staged in LDS; as1[src] is one 16B gather per edge. ----
__global__ __launch_bounds__(512) void k_bucketB(const int* __restrict__ bwp,
                                                 const int* __restrict__ tmp,
                                                 const float* __restrict__ as1,
                                                 const float* __restrict__ ad1,
                                                 int* __restrict__ col,
                                                 int* __restrict__ dloc,
                                                 float* __restrict__ wgt1,
                                                 int* __restrict__ rowptr,
                                                 int* __restrict__ degarr) {
    __shared__ int degs[256];
    __shared__ int wp[256];
    __shared__ int wsum[4];
    __shared__ float Lad[1024];
    const int b = blockIdx.x, t = threadIdx.x;
    const int n0 = b << 8;
    const int beg = b * BCAP;
    const int end = bwp[b];
    if (t < 256) degs[t] = 0;
    for (int i = t; i < 1024; i += 512) {
        int gi = n0 * 4 + i;
        Lad[i] = (gi < NODES * 4) ? ad1[gi] : 0.f;
    }
    __syncthreads();
    for (int e = beg + t; e < end; e += 512)
        atomicAdd(&degs[tmp[e] & 255], 1);
    __syncthreads();
    int d = 0, incl = 0;
    const int lane = t & 63, w = t >> 6;
    if (t < 256) {
        d = degs[t];
        incl = d;
#pragma unroll
        for (int s = 1; s < 64; s <<= 1) {
            int u = __shfl_up(incl, s);
            if (lane >= s) incl += u;
        }
        if (lane == 63) wsum[w] = incl;
    }
    __syncthreads();
    if (t == 0) {
        int r = 0;
#pragma unroll
        for (int i = 0; i < 4; i++) { int x = wsum[i]; wsum[i] = r; r += x; }
    }
    __syncthreads();
    if (t < 256) {
        const int excl = incl - d + wsum[w] + beg;
        const int nidx = n0 + t;
        if (nidx < NODES) { rowptr[nidx] = excl; degarr[nidx] = d; }
        wp[t] = excl;
    }
    __syncthreads();
    for (int e = beg + t; e < end; e += 512) {
        int v = tmp[e];
        int dl = v & 255;
        int s = v >> 8;
        int p = atomicAdd(&wp[dl], 1);
        col[p] = s;
        dloc[p] = dl;
        float4 a = *(const float4*)(as1 + s * 4);
        f32x4a wv;
        wv.x = __expf(lrelu(a.x + Lad[dl * 4 + 0]));
        wv.y = __expf(lrelu(a.y + Lad[dl * 4 + 1]));
        wv.z = __expf(lrelu(a.z + Lad[dl * 4 + 2]));
        wv.w = __expf(lrelu(a.w + Lad[dl * 4 + 3]));
        *(f32x4a*)(wgt1 + (size_t)p * 4) = wv;
    }
}

// ---- layer-1 aggregation: one wave per dst node; adaptive 32/16 epochs;
//      weights streamed from wgt1 (no as-gather, no exp in the loop). ----
__global__ __launch_bounds__(256) void k_agg1(const unsigned short* __restrict__ h1b,
                                              const float* __restrict__ as1,
                                              const float* __restrict__ ad1,
                                              const int* __restrict__ rowptr,
                                              const int* __restrict__ degarr,
                                              const int* __restrict__ col,
                                              const float* __restrict__ wgt1,
                                              const float* __restrict__ b1,
                                              unsigned short* __restrict__ out1) {
    int wid = (blockIdx.x * 256 + threadIdx.x) >> 6;
    if (wid >= NODES) return;
    const int lane = threadIdx.x & 63;
    const int q  = lane >> 4;       // edge sub-slot
    const int ll = lane & 15;       // channel group
    const int fh = ll >> 2;         // head
    const int n = wid;
    const int rs = rowptr[n];
    const int re = rs + degarr[n];
    const unsigned lo = (unsigned)(ll << 4);

    float den = 0.f;
    float ac[8];
#pragma unroll
    for (int k = 0; k < 8; k++) ac[k] = 0.f;

    int base = rs;
    for (; re - base > 16; base += 32) {
        int4a ca = *(const int4a*)(col + base + q * 4);
        int4a cb = *(const int4a*)(col + base + 16 + q * 4);
        const int ia = base + q * 4;
        const int ib = base + 16 + q * 4;
        int c0 = (ia + 0 < re) ? ca.x : n;
        int c1 = (ia + 1 < re) ? ca.y : n;
        int c2 = (ia + 2 < re) ? ca.z : n;
        int c3 = (ia + 3 < re) ? ca.w : n;
        int c4 = (ib + 0 < re) ? cb.x : n;
        int c5 = (ib + 1 < re) ? cb.y : n;
        int c6 = (ib + 2 < re) ? cb.z : n;
        int c7 = (ib + 3 < re) ? cb.w : n;
        float w0 = wgt1[(ia + 0) * 4 + fh]; if (ia + 0 >= re) w0 = 0.f;
        float w1 = wgt1[(ia + 1) * 4 + fh]; if (ia + 1 >= re) w1 = 0.f;
        float w2 = wgt1[(ia + 2) * 4 + fh]; if (ia + 2 >= re) w2 = 0.f;
        float w3 = wgt1[(ia + 3) * 4 + fh]; if (ia + 3 >= re) w3 = 0.f;
        float w4 = wgt1[(ib + 0) * 4 + fh]; if (ib + 0 >= re) w4 = 0.f;
        float w5 = wgt1[(ib + 1) * 4 + fh]; if (ib + 1 >= re) w5 = 0.f;
        float w6 = wgt1[(ib + 2) * 4 + fh]; if (ib + 2 >= re) w6 = 0.f;
        float w7 = wgt1[(ib + 3) * 4 + fh]; if (ib + 3 >= re) w7 = 0.f;
        den += ((w0 + w1) + (w2 + w3)) + ((w4 + w5) + (w6 + w7));
        uint4 p0 = *(const uint4*)((const char*)h1b + (((unsigned)c0 << 8) + lo));
        uint4 p1 = *(const uint4*)((const char*)h1b + (((unsigned)c1 << 8) + lo));
        uint4 p2 = *(const uint4*)((const char*)h1b + (((unsigned)c2 << 8) + lo));
        uint4 p3 = *(const uint4*)((const char*)h1b + (((unsigned)c3 << 8) + lo));
        uint4 p4 = *(const uint4*)((const char*)h1b + (((unsigned)c4 << 8) + lo));
        uint4 p5 = *(const uint4*)((const char*)h1b + (((unsigned)c5 << 8) + lo));
        uint4 p6 = *(const uint4*)((const char*)h1b + (((unsigned)c6 << 8) + lo));
        uint4 p7 = *(const uint4*)((const char*)h1b + (((unsigned)c7 << 8) + lo));
        acc8(w0, p0, ac); acc8(w1, p1, ac); acc8(w2, p2, ac); acc8(w3, p3, ac);
        acc8(w4, p4, ac); acc8(w5, p5, ac); acc8(w6, p6, ac); acc8(w7, p7, ac);
    }
    if (base < re) {
        int4a ca = *(const int4a*)(col + base + q * 4);
        const int ia = base + q * 4;
        int c0 = (ia + 0 < re) ? ca.x : n;
        int c1 = (ia + 1 < re) ? ca.y : n;
        int c2 = (ia + 2 < re) ? ca.z : n;
        int c3 = (ia + 3 < re) ? ca.w : n;
        float w0 = wgt1[(ia + 0) * 4 + fh]; if (ia + 0 >= re) w0 = 0.f;
        float w1 = wgt1[(ia + 1) * 4 + fh]; if (ia + 1 >= re) w1 = 0.f;
        float w2 = wgt1[(ia + 2) * 4 + fh]; if (ia + 2 >= re) w2 = 0.f;
        float w3 = wgt1[(ia + 3) * 4 + fh]; if (ia + 3 >= re) w3 = 0.f;
        den += (w0 + w1) + (w2 + w3);
        uint4 p0 = *(const uint4*)((const char*)h1b + (((unsigned)c0 << 8) + lo));
        uint4 p1 = *(const uint4*)((const char*)h1b + (((unsigned)c1 << 8) + lo));
        uint4 p2 = *(const uint4*)((const char*)h1b + (((unsigned)c2 << 8) + lo));
        uint4 p3 = *(const uint4*)((const char*)h1b + (((unsigned)c3 << 8) + lo));
        acc8(w0, p0, ac); acc8(w1, p1, ac); acc8(w2, p2, ac); acc8(w3, p3, ac);
    }
    den += __shfl_xor(den, 16);
    den += __shfl_xor(den, 32);
#pragma unroll
    for (int k = 0; k < 8; k++) {
        ac[k] += __shfl_xor(ac[k], 16);
        ac[k] += __shfl_xor(ac[k], 32);
    }
    const float wself = __expf(lrelu(as1[n * HEADS + fh] + ad1[n * HEADS + fh]));
    den += wself;
    if (q == 0) {
        unsigned offs = ((unsigned)n << 8) + lo;
        uint4 sp = *(const uint4*)((const char*)h1b + offs);
        float sv[8] = {bflo(sp.x), bfhi(sp.x), bflo(sp.y), bfhi(sp.y),
                       bflo(sp.z), bfhi(sp.z), bflo(sp.w), bfhi(sp.w)};
        float4 bv0 = *(const float4*)(b1 + ll * 8);
        float4 bv1 = *(const float4*)(b1 + ll * 8 + 4);
        float bb[8] = {bv0.x, bv0.y, bv0.z, bv0.w, bv1.x, bv1.y, bv1.z, bv1.w};
        const float inv = 1.f / den;
        float o[8];
#pragma unroll
        for (int k = 0; k < 8; k++)
            o[k] = fmaxf(fmaf(wself, sv[k], ac[k]) * inv + bb[k], 0.f);
        uint4 pk;
        pk.x = cvtpk(o[0], o[1]);
        pk.y = cvtpk(o[2], o[3]);
        pk.z = cvtpk(o[4], o[5]);
        pk.w = cvtpk(o[6], o[7]);
        *(uint4*)(out1 + (size_t)n * C1 + ll * 8) = pk;
    }
}

// ---- GEMM2 (MFMA bf16, fused att2): h2b[N,40](bf16, 80B rows) ; as2/ad2 ----
__global__ __launch_bounds__(256) void k_gemm2(const unsigned short* __restrict__ out1b,
                                               const unsigned short* __restrict__ w2t,
                                               const float* __restrict__ AS,
                                               const float* __restrict__ AD,
                                               unsigned short* __restrict__ h2b,
                                               float* __restrict__ as2,
                                               float* __restrict__ ad2) {
    __shared__ unsigned short Asm[64][136];
    __shared__ unsigned short Wt2[48][136];
    __shared__ float Cc[64][52];
    const int t = threadIdx.x;
    const int row0 = blockIdx.x * 64;

    for (int p = t; p < 8 * 136; p += 256) Wt2[40 + p / 136][p % 136] = 0;
    for (int p = t; p < 640; p += 256) {
        int n = p >> 4, k8 = (p & 15) * 8;
        *(uint4*)(&Wt2[n][k8]) = *(const uint4*)(w2t + n * 128 + k8);
    }
    {
        int r = t >> 2, c0 = (t & 3) * 32;
        int gr = row0 + r;
        if (gr < NODES) {
#pragma unroll
            for (int i = 0; i < 4; i++)
                *(uint4*)(&Asm[r][c0 + i * 8]) =
                    *(const uint4*)(out1b + (size_t)gr * C1 + c0 + i * 8);
        } else {
            uint4 z = make_uint4(0, 0, 0, 0);
#pragma unroll
            for (int i = 0; i < 4; i++) *(uint4*)(&Asm[r][c0 + i * 8]) = z;
        }
    }
    __syncthreads();

    const int w = t >> 6, l = t & 63;
    const int lm = l & 15, quad = l >> 4;
    f32x4 acc[3];
#pragma unroll
    for (int ct = 0; ct < 3; ct++) acc[ct] = (f32x4){0.f, 0.f, 0.f, 0.f};
#pragma unroll
    for (int kt = 0; kt < 4; kt++) {
        bf16x8 a = *(const bf16x8*)(&Asm[w * 16 + lm][kt * 32 + quad * 8]);
#pragma unroll
        for (int ct = 0; ct < 3; ct++) {
            bf16x8 b = *(const bf16x8*)(&Wt2[ct * 16 + lm][kt * 32 + quad * 8]);
            acc[ct] = __builtin_amdgcn_mfma_f32_16x16x32_bf16(a, b, acc[ct], 0, 0, 0);
        }
    }
    __syncthreads();
#pragma unroll
    for (int ct = 0; ct < 3; ct++)
#pragma unroll
        for (int r = 0; r < 4; r++)
            Cc[w * 16 + quad * 4 + r][ct * 16 + lm] = acc[ct][r];
    __syncthreads();
    {
        int r = t >> 2, c0 = (t & 3) * 10;
        int gr = row0 + r;
        if (gr < NODES) {
#pragma unroll
            for (int i = 0; i < 5; i++) {
                int c = c0 + i * 2;
                unsigned pk = cvtpk(Cc[r][c], Cc[r][c + 1]);
                *(unsigned*)(h2b + (size_t)gr * 40 + c) = pk;
            }
            float s = 0.f, d = 0.f;
#pragma unroll
            for (int j = 0; j < 10; j++) {
                float v = Cc[r][c0 + j];
                s = fmaf(v, AS[c0 + j], s);
                d = fmaf(v, AD[c0 + j], d);
            }
            s += __shfl_xor(s, 1); s += __shfl_xor(s, 2);
            d += __shfl_xor(d, 1); d += __shfl_xor(d, 2);
            if ((t & 3) == 0) { as2[gr] = s; ad2[gr] = d; }
        }
    }
}

// ---- per-edge layer-2 weight precompute: wgt2[e] = exp(lrelu(as2[col]+ad2[dst])).
//      ad2 for the bucket's 256 dst nodes in LDS; as2 is L2-resident (200 KB). ----
__global__ __launch_bounds__(512) void k_wgt2(const int* __restrict__ bwp,
                                              const int* __restrict__ col,
                                              const int* __restrict__ dloc,
                                              const float* __restrict__ as2,
                                              const float* __restrict__ ad2,
                                              float* __restrict__ wgt2) {
    __shared__ float Lad[256];
    const int b = blockIdx.x, t = threadIdx.x;
    const int n0 = b << 8;
    if (t < 256) {
        int gi = n0 + t;
        Lad[t] = (gi < NODES) ? ad2[gi] : 0.f;
    }
    __syncthreads();
    const int beg = b * BCAP, end = bwp[b];
    for (int e = beg + t; e < end; e += 512)
        wgt2[e] = __expf(lrelu(as2[col[e]] + Lad[dloc[e]]));
}

// ---- layer-2 aggregation: one wave per dst node; adaptive 32/16 epochs;
//      weights streamed from wgt2 (contiguous float4/float2 loads). ----
__global__ __launch_bounds__(256) void k_agg2(const unsigned short* __restrict__ h2b,
                                              const float* __restrict__ as2,
                                              const float* __restrict__ ad2,
                                              const int* __restrict__ rowptr,
                                              const int* __restrict__ degarr,
                                              const int* __restrict__ col,
                                              const float* __restrict__ wgt2,
                                              const float* __restrict__ b2,
                                              float* __restrict__ out) {
    int wid = (blockIdx.x * 256 + threadIdx.x) >> 6;
    if (wid >= NODES) return;
    const int lane = threadIdx.x & 63;
    const int q8 = lane >> 3, l8 = lane & 7;
    const int n = wid;
    const int rs = rowptr[n];
    const int re = rs + degarr[n];
    const unsigned lo = (unsigned)(l8 << 4);

    float den = 0.f;
    float ac[8];
#pragma unroll
    for (int k = 0; k < 8; k++) ac[k] = 0.f;

    int base = rs;
    for (; re - base > 16; base += 32) {
        int4a cc = *(const int4a*)(col + base + q8 * 4);
        f32x4a wv = *(const f32x4a*)(wgt2 + base + q8 * 4);
        const int i0 = base + q8 * 4;
        int c0 = (i0 + 0 < re) ? cc.x : n;
        int c1 = (i0 + 1 < re) ? cc.y : n;
        int c2 = (i0 + 2 < re) ? cc.z : n;
        int c3 = (i0 + 3 < re) ? cc.w : n;
        float w0 = wv.x; if (i0 + 0 >= re) w0 = 0.f;
        float w1 = wv.y; if (i0 + 1 >= re) w1 = 0.f;
        float w2 = wv.z; if (i0 + 2 >= re) w2 = 0.f;
        float w3 = wv.w; if (i0 + 3 >= re) w3 = 0.f;
        den += (w0 + w1) + (w2 + w3);
        if (l8 < 5) {
            uint4 p0 = *(const uint4*)((const char*)h2b + ((unsigned)c0 * 80u + lo));
            uint4 p1 = *(const uint4*)((const char*)h2b + ((unsigned)c1 * 80u + lo));
            uint4 p2 = *(const uint4*)((const char*)h2b + ((unsigned)c2 * 80u + lo));
            uint4 p3 = *(const uint4*)((const char*)h2b + ((unsigned)c3 * 80u + lo));
            acc8(w0, p0, ac); acc8(w1, p1, ac);
            acc8(w2, p2, ac); acc8(w3, p3, ac);
        }
    }
    if (base < re) {
        int2a cc = *(const int2a*)(col + base + q8 * 2);
        f32x2a wv = *(const f32x2a*)(wgt2 + base + q8 * 2);
        const int i0 = base + q8 * 2;
        int c0 = (i0 + 0 < re) ? cc.x : n;
        int c1 = (i0 + 1 < re) ? cc.y : n;
        float w0 = wv.x; if (i0 + 0 >= re) w0 = 0.f;
        float w1 = wv.y; if (i0 + 1 >= re) w1 = 0.f;
        den += w0 + w1;
        if (l8 < 5) {
            uint4 p0 = *(const uint4*)((const char*)h2b + ((unsigned)c0 * 80u + lo));
            uint4 p1 = *(const uint4*)((const char*)h2b + ((unsigned)c1 * 80u + lo));
            acc8(w0, p0, ac); acc8(w1, p1, ac);
        }
    }
    den += __shfl_xor(den, 8);
    den += __shfl_xor(den, 16);
    den += __shfl_xor(den, 32);
#pragma unroll
    for (int k = 0; k < 8; k++) {
        ac[k] += __shfl_xor(ac[k], 8);
        ac[k] += __shfl_xor(ac[k], 16);
        ac[k] += __shfl_xor(ac[k], 32);
    }
    const float wself = __expf(lrelu(as2[n] + ad2[n]));
    den += wself;
    if (q8 == 0 && l8 < 5) {
        unsigned offs = (unsigned)n * 80u + lo;
        uint4 sp = *(const uint4*)((const char*)h2b + offs);
        float sv[8] = {bflo(sp.x), bfhi(sp.x), bflo(sp.y), bfhi(sp.y),
                       bflo(sp.z), bfhi(sp.z), bflo(sp.w), bfhi(sp.w)};
        float4 bv0 = *(const float4*)(b2 + l8 * 8);
        float4 bv1 = *(const float4*)(b2 + l8 * 8 + 4);
        float bb[8] = {bv0.x, bv0.y, bv0.z, bv0.w, bv1.x, bv1.y, bv1.z, bv1.w};
        float o[8];
#pragma unroll
        for (int k = 0; k < 8; k++)
            o[k] = (ac[k] + wself * sv[k]) / den + bb[k];
        *(float4*)(out + (size_t)n * CLS + l8 * 8) =
            make_float4(o[0], o[1], o[2], o[3]);
        *(float4*)(out + (size_t)n * CLS + l8 * 8 + 4) =
            make_float4(o[4], o[5], o[6], o[7]);
    }
}

extern "C" void kernel_launch(void* const* d_in, const int* in_sizes, int n_in,
                              void* d_out, int out_size, void* d_ws, size_t ws_size,
                              hipStream_t stream) {
    const float* x     = (const float*)d_in[0];
    const int*   ei    = (const int*)d_in[1];
    const float* W1    = (const float*)d_in[2];
    const float* aS1   = (const float*)d_in[3];
    const float* aD1   = (const float*)d_in[4];
    const float* b1    = (const float*)d_in[5];
    const float* W2    = (const float*)d_in[6];
    const float* aS2   = (const float*)d_in[7];
    const float* aD2   = (const float*)d_in[8];
    const float* b2    = (const float*)d_in[9];
    float* out = (float*)d_out;
    const int E = in_sizes[1] / 2;
    const int* src = ei;
    const int* dst = ei + E;

    char* ws = (char*)d_ws;
    size_t off = 0;
    auto alloc = [&](size_t bytes) -> char* {
        char* p = ws + off;
        off += (bytes + 255) & ~(size_t)255;
        return p;
    };
    unsigned short* h1b  = (unsigned short*)alloc((size_t)NODES * C1 * 2);
    unsigned short* out1 = (unsigned short*)alloc((size_t)NODES * C1 * 2);
    unsigned short* h2b  = (unsigned short*)alloc((size_t)NODES * 40 * 2);
    float* as1    = (float*)alloc((size_t)NODES * HEADS * 4);
    float* ad1    = (float*)alloc((size_t)NODES * HEADS * 4);
    float* as2    = (float*)alloc((size_t)NODES * 4);
    float* ad2    = (float*)alloc((size_t)NODES * 4);
    int* rowptr   = (int*)alloc((size_t)NODES * 4);
    int* degarr   = (int*)alloc((size_t)NODES * 4);
    int* col      = (int*)alloc((size_t)NBUCK * BCAP * 4 + 1024);   // +slack
    int* tmp      = (int*)alloc((size_t)NBUCK * BCAP * 4 + 1024);
    int* dloc     = (int*)alloc((size_t)NBUCK * BCAP * 4 + 1024);
    float* wgt1   = (float*)alloc((size_t)NBUCK * BCAP * 16 + 4096); // 4 f32/edge
    float* wgt2   = (float*)alloc((size_t)NBUCK * BCAP * 4 + 1024);  // 1 f32/edge
    unsigned short* w1t = (unsigned short*)alloc((size_t)FIN * C1 * 2);
    unsigned short* w2t = (unsigned short*)alloc((size_t)CLS * 128 * 2);
    int* bwp      = (int*)alloc((size_t)NBUCK * 4);

    const int GB1 = (NODES + 63) / 64;           // 782 gemm1 blocks
    const int GBA = (E + EPB - 1) / EPB;         // bucketA blocks

    k_prep<<<9, 256, 0, stream>>>(W1, W2, w1t, w2t, bwp);
    k_front<<<GB1 + GBA, 256, 0, stream>>>(x, w1t, aS1, aD1, h1b, as1, ad1,
                                           src, dst, E, bwp, tmp, GB1);
    k_bucketB<<<NBUCK, 512, 0, stream>>>(bwp, tmp, as1, ad1, col, dloc, wgt1,
                                         rowptr, degarr);
    k_agg1<<<(NODES * 64) / 256, 256, 0, stream>>>(h1b, as1, ad1, rowptr, degarr,
                                                   col, wgt1, b1, out1);
    k_gemm2<<<(NODES + 63) / 64, 256, 0, stream>>>(out1, w2t, aS2, aD2, h2b, as2, ad2);
    k_wgt2<<<NBUCK, 512, 0, stream>>>(bwp, col, dloc, as2, ad2, wgt2);
    k_agg2<<<(NODES * 64) / 256, 256, 0, stream>>>(h2b, as2, ad2, rowptr, degarr,
                                                   col, wgt2, b2, out);
}

// Round 7
// 188.166 us; speedup vs baseline: 1.0985x; 1.0985x over previous
//
#include <hip/hip_runtime.h>
#include <cstdint>

#define NODES 50000
#define FIN   128
#define C1    128   // HEADS*HID
#define HEADS 4
#define HID   32
#define CLS   40
#define SLOPE 0.2f

#define NBUCK ((NODES + 255) >> 8)   // 196
#define EPB 2048                     // edges per bucketA block
#define BCAP 8192                    // fixed bucket capacity (max actual ~4.3k)

__device__ __forceinline__ float lrelu(float v) { return v > 0.f ? v : SLOPE * v; }

__device__ __forceinline__ unsigned short f2bf(float f) {
    union { float f; unsigned u; } v; v.f = f;
    unsigned u = v.u;
    return (unsigned short)((u + 0x7FFFu + ((u >> 16) & 1u)) >> 16);
}
__device__ __forceinline__ float bf2f(unsigned short b) {
    union { unsigned u; float f; } v; v.u = ((unsigned)b) << 16;
    return v.f;
}
__device__ __forceinline__ float bflo(unsigned u) {
    union { unsigned x; float f; } v; v.x = u << 16; return v.f;
}
__device__ __forceinline__ float bfhi(unsigned u) {
    union { unsigned x; float f; } v; v.x = u & 0xffff0000u; return v.f;
}
// HW packed f32->bf16 (RNE): lo16=bf16(a), hi16=bf16(b)
__device__ __forceinline__ unsigned cvtpk(float a, float b) {
    unsigned r;
    asm("v_cvt_pk_bf16_f32 %0, %1, %2" : "=v"(r) : "v"(a), "v"(b));
    return r;
}

typedef __attribute__((ext_vector_type(8))) short bf16x8;
typedef __attribute__((ext_vector_type(4))) float f32x4;
typedef __attribute__((ext_vector_type(4), aligned(4))) int int4a;
typedef __attribute__((ext_vector_type(2), aligned(4))) int int2a;

// accumulate one edge's 16B chunk (8 bf16 channels) with weight w
__device__ __forceinline__ void acc8(float w, uint4 p, float* ac) {
    ac[0] = fmaf(w, bflo(p.x), ac[0]); ac[1] = fmaf(w, bfhi(p.x), ac[1]);
    ac[2] = fmaf(w, bflo(p.y), ac[2]); ac[3] = fmaf(w, bfhi(p.y), ac[3]);
    ac[4] = fmaf(w, bflo(p.z), ac[4]); ac[5] = fmaf(w, bfhi(p.z), ac[5]);
    ac[6] = fmaf(w, bflo(p.w), ac[6]); ac[7] = fmaf(w, bfhi(p.w), ac[7]);
}

// ---- prep: 9 blocks. b<8: W1 16-row transpose slice -> w1t bf16.
//      b==8: W2 -> w2t bf16 transposed + bwp init. ----
__global__ __launch_bounds__(256) void k_prep(const float* __restrict__ W1,
                                              const float* __restrict__ W2,
                                              unsigned short* __restrict__ w1t,
                                              unsigned short* __restrict__ w2t,
                                              int* __restrict__ bwp) {
    const int b = blockIdx.x, t = threadIdx.x;
    if (b < 8) {
        __shared__ unsigned short Tb[16][136];
        const int n0 = b * 16;
        const int k = t & 127, g = t >> 7;
#pragma unroll
        for (int i = 0; i < 8; i++)
            Tb[g * 8 + i][k] = f2bf(W1[(size_t)k * C1 + n0 + g * 8 + i]);
        __syncthreads();
        {
            int nl = t >> 4, k8 = (t & 15) * 8;
            *(uint4*)(w1t + (n0 + nl) * 128 + k8) = *(uint4*)(&Tb[nl][k8]);
        }
    } else {
        for (int p = t; p < CLS * 128; p += 256) {
            int n = p >> 7, k = p & 127;
            w2t[n * 128 + k] = f2bf(W2[(size_t)k * CLS + n]);
        }
        if (t < NBUCK) bwp[t] = t * BCAP;
    }
}

// ---- front: blocks [0,GB1) = GEMM1 (MFMA bf16 + fused att1);
//             blocks [GB1,..) = bucketA (independent inputs/outputs) ----
__global__ __launch_bounds__(256) void k_front(const float* __restrict__ X,
                                               const unsigned short* __restrict__ w1t,
                                               const float* __restrict__ AS,
                                               const float* __restrict__ AD,
                                               unsigned short* __restrict__ h1b,
                                               float* __restrict__ as1,
                                               float* __restrict__ ad1,
                                               const int* __restrict__ src,
                                               const int* __restrict__ dst, int E,
                                               int* __restrict__ bwp,
                                               int* __restrict__ tmp, int GB1) {
    __shared__ unsigned short Asm[64][136];
    __shared__ unsigned short Wt[128][136];
    __shared__ int cnt[NBUCK];
    __shared__ int bbs[NBUCK];
    const int t = threadIdx.x;

    if (blockIdx.x >= GB1) {
        // ---------------- bucketA body ----------------
        for (int i = t; i < NBUCK; i += 256) cnt[i] = 0;
        __syncthreads();
        const int e0 = (blockIdx.x - GB1) * EPB;
        int v[8], rb[8];
#pragma unroll
        for (int k = 0; k < 8; k++) {
            int e = e0 + k * 256 + t;
            rb[k] = -1;
            if (e < E) {
                int d = dst[e], s = src[e];
                int b = d >> 8;
                int r = atomicAdd(&cnt[b], 1);
                v[k] = (s << 8) | (d & 255);
                rb[k] = (r << 8) | b;
            }
        }
        __syncthreads();
        for (int i = t; i < NBUCK; i += 256) {
            int c = cnt[i];
            bbs[i] = c ? atomicAdd(&bwp[i], c) : 0;
        }
        __syncthreads();
#pragma unroll
        for (int k = 0; k < 8; k++) {
            if (rb[k] >= 0) {
                int b = rb[k] & 255;
                int r = rb[k] >> 8;
                tmp[bbs[b] + r] = v[k];
            }
        }
        return;
    }

    // ---------------- GEMM1 body ----------------
    const int row0 = blockIdx.x * 64;
#pragma unroll
    for (int i = 0; i < 8; i++) {
        int p = i * 256 + t;
        int n = p >> 4, k8 = (p & 15) * 8;
        *(uint4*)(&Wt[n][k8]) = *(const uint4*)(w1t + n * 128 + k8);
    }
    {
        int r = t >> 2, c0 = (t & 3) * 32;
        int gr = row0 + r;
        if (gr < NODES) {
#pragma unroll
            for (int i = 0; i < 4; i++) {
                float4 va = *(const float4*)(X + (size_t)gr * FIN + c0 + i * 8);
                float4 vb = *(const float4*)(X + (size_t)gr * FIN + c0 + i * 8 + 4);
                uint4 pk;
                pk.x = cvtpk(va.x, va.y);
                pk.y = cvtpk(va.z, va.w);
                pk.z = cvtpk(vb.x, vb.y);
                pk.w = cvtpk(vb.z, vb.w);
                *(uint4*)(&Asm[r][c0 + i * 8]) = pk;
            }
        } else {
            uint4 z = make_uint4(0, 0, 0, 0);
#pragma unroll
            for (int i = 0; i < 4; i++) *(uint4*)(&Asm[r][c0 + i * 8]) = z;
        }
    }
    __syncthreads();

    const int w = t >> 6, l = t & 63;
    const int lm = l & 15, quad = l >> 4;
    f32x4 acc[8];
#pragma unroll
    for (int ct = 0; ct < 8; ct++) acc[ct] = (f32x4){0.f, 0.f, 0.f, 0.f};
#pragma unroll
    for (int kt = 0; kt < 4; kt++) {
        bf16x8 a = *(const bf16x8*)(&Asm[w * 16 + lm][kt * 32 + quad * 8]);
#pragma unroll
        for (int ct = 0; ct < 8; ct++) {
            bf16x8 b = *(const bf16x8*)(&Wt[ct * 16 + lm][kt * 32 + quad * 8]);
            acc[ct] = __builtin_amdgcn_mfma_f32_16x16x32_bf16(a, b, acc[ct], 0, 0, 0);
        }
    }
    __syncthreads();
#pragma unroll
    for (int ct = 0; ct < 8; ct++)
#pragma unroll
        for (int r = 0; r < 4; r++)
            Asm[w * 16 + quad * 4 + r][ct * 16 + lm] = f2bf(acc[ct][r]);
    __syncthreads();
    {
        int r = t >> 2, c0 = (t & 3) * 32;
        int gr = row0 + r;
        if (gr < NODES) {
#pragma unroll
            for (int i = 0; i < 4; i++)
                *(uint4*)(h1b + (size_t)gr * C1 + c0 + i * 8) =
                    *(uint4*)(&Asm[r][c0 + i * 8]);
        }
    }
    {
        // att1: vectorized LDS reads (uint4) + float4 AS/AD loads
        int r = t >> 2, h = t & 3;
        int gr = row0 + r;
        if (gr < NODES) {
            float s = 0.f, d = 0.f;
#pragma unroll
            for (int i = 0; i < 4; i++) {
                uint4 hv = *(const uint4*)(&Asm[r][h * 32 + i * 8]);
                float4 a0 = *(const float4*)(AS + h * HID + i * 8);
                float4 a1 = *(const float4*)(AS + h * HID + i * 8 + 4);
                float4 d0 = *(const float4*)(AD + h * HID + i * 8);
                float4 d1 = *(const float4*)(AD + h * HID + i * 8 + 4);
                float v0 = bflo(hv.x), v1 = bfhi(hv.x), v2 = bflo(hv.y), v3 = bfhi(hv.y);
                float v4 = bflo(hv.z), v5 = bfhi(hv.z), v6 = bflo(hv.w), v7 = bfhi(hv.w);
                s = fmaf(v0, a0.x, s); s = fmaf(v1, a0.y, s);
                s = fmaf(v2, a0.z, s); s = fmaf(v3, a0.w, s);
                s = fmaf(v4, a1.x, s); s = fmaf(v5, a1.y, s);
                s = fmaf(v6, a1.z, s); s = fmaf(v7, a1.w, s);
                d = fmaf(v0, d0.x, d); d = fmaf(v1, d0.y, d);
                d = fmaf(v2, d0.z, d); d = fmaf(v3, d0.w, d);
                d = fmaf(v4, d1.x, d); d = fmaf(v5, d1.y, d);
                d = fmaf(v6, d1.z, d); d = fmaf(v7, d1.w, d);
            }
            as1[gr * HEADS + h] = s;
            ad1[gr * HEADS + h] = d;
        }
    }
}

// ---- pass B: per-bucket degree+scan -> rowptr/deg, scatter col.
//      512 threads/block (196 blocks only -> occupancy-starved at 256). ----
__global__ __launch_bounds__(512) void k_bucketB(const int* __restrict__ bwp,
                                                 const int* __restrict__ tmp,
                                                 int* __restrict__ col,
                                                 int* __restrict__ rowptr,
                                                 int* __restrict__ degarr) {
    __shared__ int degs[256];
    __shared__ int wp[256];
    __shared__ int wsum[4];
    const int b = blockIdx.x, t = threadIdx.x;
    const int n0 = b << 8;
    const int beg = b * BCAP;
    const int end = bwp[b];
    if (t < 256) degs[t] = 0;
    __syncthreads();
    for (int e = beg + t; e < end; e += 512)
        atomicAdd(&degs[tmp[e] & 255], 1);
    __syncthreads();
    int d = 0, incl = 0;
    const int lane = t & 63, w = t >> 6;
    if (t < 256) {
        d = degs[t];
        incl = d;
#pragma unroll
        for (int s = 1; s < 64; s <<= 1) {
            int u = __shfl_up(incl, s);
            if (lane >= s) incl += u;
        }
        if (lane == 63) wsum[w] = incl;
    }
    __syncthreads();
    if (t == 0) {
        int r = 0;
#pragma unroll
        for (int i = 0; i < 4; i++) { int x = wsum[i]; wsum[i] = r; r += x; }
    }
    __syncthreads();
    if (t < 256) {
        const int excl = incl - d + wsum[w] + beg;
        const int nidx = n0 + t;
        if (nidx < NODES) { rowptr[nidx] = excl; degarr[nidx] = d; }
        wp[t] = excl;
    }
    __syncthreads();
    for (int e = beg + t; e < end; e += 512) {
        int v = tmp[e];
        int p = atomicAdd(&wp[v & 255], 1);
        col[p] = v >> 8;
    }
}

// ---- layer-1 aggregation: one wave per dst node; adaptive 32/16 epochs
//      (R4-winner structure). ----
__global__ __launch_bounds__(256) void k_agg1(const unsigned short* __restrict__ h1b,
                                              const float* __restrict__ as1,
                                              const float* __restrict__ ad1,
                                              const int* __restrict__ rowptr,
                                              const int* __restrict__ degarr,
                                              const int* __restrict__ col,
                                              const float* __restrict__ b1,
                                              unsigned short* __restrict__ out1) {
    int wid = (blockIdx.x * 256 + threadIdx.x) >> 6;
    if (wid >= NODES) return;
    const int lane = threadIdx.x & 63;
    const int q  = lane >> 4;       // edge sub-slot
    const int ll = lane & 15;       // channel group
    const int fh = ll >> 2;         // head
    const int n = wid;
    const float adn = ad1[n * HEADS + fh];
    const int rs = rowptr[n];
    const int re = rs + degarr[n];
    const unsigned lo = (unsigned)(ll << 4);

    float den = 0.f;
    float ac[8];
#pragma unroll
    for (int k = 0; k < 8; k++) ac[k] = 0.f;

    int base = rs;
    for (; re - base > 16; base += 32) {
        // 32-wide predicated epoch
        int4a ca = *(const int4a*)(col + base + q * 4);
        int4a cb = *(const int4a*)(col + base + 16 + q * 4);
        const int ia = base + q * 4;
        const int ib = base + 16 + q * 4;
        int c0 = (ia + 0 < re) ? ca.x : n;
        int c1 = (ia + 1 < re) ? ca.y : n;
        int c2 = (ia + 2 < re) ? ca.z : n;
        int c3 = (ia + 3 < re) ? ca.w : n;
        int c4 = (ib + 0 < re) ? cb.x : n;
        int c5 = (ib + 1 < re) ? cb.y : n;
        int c6 = (ib + 2 < re) ? cb.z : n;
        int c7 = (ib + 3 < re) ? cb.w : n;
        float w0 = __expf(lrelu(as1[c0 * HEADS + fh] + adn)); if (ia + 0 >= re) w0 = 0.f;
        float w1 = __expf(lrelu(as1[c1 * HEADS + fh] + adn)); if (ia + 1 >= re) w1 = 0.f;
        float w2 = __expf(lrelu(as1[c2 * HEADS + fh] + adn)); if (ia + 2 >= re) w2 = 0.f;
        float w3 = __expf(lrelu(as1[c3 * HEADS + fh] + adn)); if (ia + 3 >= re) w3 = 0.f;
        float w4 = __expf(lrelu(as1[c4 * HEADS + fh] + adn)); if (ib + 0 >= re) w4 = 0.f;
        float w5 = __expf(lrelu(as1[c5 * HEADS + fh] + adn)); if (ib + 1 >= re) w5 = 0.f;
        float w6 = __expf(lrelu(as1[c6 * HEADS + fh] + adn)); if (ib + 2 >= re) w6 = 0.f;
        float w7 = __expf(lrelu(as1[c7 * HEADS + fh] + adn)); if (ib + 3 >= re) w7 = 0.f;
        den += ((w0 + w1) + (w2 + w3)) + ((w4 + w5) + (w6 + w7));
        uint4 p0 = *(const uint4*)((const char*)h1b + (((unsigned)c0 << 8) + lo));
        uint4 p1 = *(const uint4*)((const char*)h1b + (((unsigned)c1 << 8) + lo));
        uint4 p2 = *(const uint4*)((const char*)h1b + (((unsigned)c2 << 8) + lo));
        uint4 p3 = *(const uint4*)((const char*)h1b + (((unsigned)c3 << 8) + lo));
        uint4 p4 = *(const uint4*)((const char*)h1b + (((unsigned)c4 << 8) + lo));
        uint4 p5 = *(const uint4*)((const char*)h1b + (((unsigned)c5 << 8) + lo));
        uint4 p6 = *(const uint4*)((const char*)h1b + (((unsigned)c6 << 8) + lo));
        uint4 p7 = *(const uint4*)((const char*)h1b + (((unsigned)c7 << 8) + lo));
        acc8(w0, p0, ac); acc8(w1, p1, ac); acc8(w2, p2, ac); acc8(w3, p3, ac);
        acc8(w4, p4, ac); acc8(w5, p5, ac); acc8(w6, p6, ac); acc8(w7, p7, ac);
    }
    if (base < re) {
        // 16-wide predicated tail
        int4a ca = *(const int4a*)(col + base + q * 4);
        const int ia = base + q * 4;
        int c0 = (ia + 0 < re) ? ca.x : n;
        int c1 = (ia + 1 < re) ? ca.y : n;
        int c2 = (ia + 2 < re) ? ca.z : n;
        int c3 = (ia + 3 < re) ? ca.w : n;
        float w0 = __expf(lrelu(as1[c0 * HEADS + fh] + adn)); if (ia + 0 >= re) w0 = 0.f;
        float w1 = __expf(lrelu(as1[c1 * HEADS + fh] + adn)); if (ia + 1 >= re) w1 = 0.f;
        float w2 = __expf(lrelu(as1[c2 * HEADS + fh] + adn)); if (ia + 2 >= re) w2 = 0.f;
        float w3 = __expf(lrelu(as1[c3 * HEADS + fh] + adn)); if (ia + 3 >= re) w3 = 0.f;
        den += (w0 + w1) + (w2 + w3);
        uint4 p0 = *(const uint4*)((const char*)h1b + (((unsigned)c0 << 8) + lo));
        uint4 p1 = *(const uint4*)((const char*)h1b + (((unsigned)c1 << 8) + lo));
        uint4 p2 = *(const uint4*)((const char*)h1b + (((unsigned)c2 << 8) + lo));
        uint4 p3 = *(const uint4*)((const char*)h1b + (((unsigned)c3 << 8) + lo));
        acc8(w0, p0, ac); acc8(w1, p1, ac); acc8(w2, p2, ac); acc8(w3, p3, ac);
    }
    den += __shfl_xor(den, 16);
    den += __shfl_xor(den, 32);
#pragma unroll
    for (int k = 0; k < 8; k++) {
        ac[k] += __shfl_xor(ac[k], 16);
        ac[k] += __shfl_xor(ac[k], 32);
    }
    const float wself = __expf(lrelu(as1[n * HEADS + fh] + adn));
    den += wself;
    if (q == 0) {
        unsigned offs = ((unsigned)n << 8) + lo;
        uint4 sp = *(const uint4*)((const char*)h1b + offs);
        float sv[8] = {bflo(sp.x), bfhi(sp.x), bflo(sp.y), bfhi(sp.y),
                       bflo(sp.z), bfhi(sp.z), bflo(sp.w), bfhi(sp.w)};
        float4 bv0 = *(const float4*)(b1 + ll * 8);
        float4 bv1 = *(const float4*)(b1 + ll * 8 + 4);
        float bb[8] = {bv0.x, bv0.y, bv0.z, bv0.w, bv1.x, bv1.y, bv1.z, bv1.w};
        const float inv = 1.f / den;
        float o[8];
#pragma unroll
        for (int k = 0; k < 8; k++)
            o[k] = fmaxf(fmaf(wself, sv[k], ac[k]) * inv + bb[k], 0.f);
        uint4 pk;
        pk.x = cvtpk(o[0], o[1]);
        pk.y = cvtpk(o[2], o[3]);
        pk.z = cvtpk(o[4], o[5]);
        pk.w = cvtpk(o[6], o[7]);
        *(uint4*)(out1 + (size_t)n * C1 + ll * 8) = pk;
    }
}

// ---- GEMM2 (MFMA bf16, fused att2): h2b[N,40](bf16, 80B rows) ; as2/ad2 ----
__global__ __launch_bounds__(256) void k_gemm2(const unsigned short* __restrict__ out1b,
                                               const unsigned short* __restrict__ w2t,
                                               const float* __restrict__ AS,
                                               const float* __restrict__ AD,
                                               unsigned short* __restrict__ h2b,
                                               float* __restrict__ as2,
                                               float* __restrict__ ad2) {
    __shared__ unsigned short Asm[64][136];
    __shared__ unsigned short Wt2[48][136];
    __shared__ float Cc[64][52];
    const int t = threadIdx.x;
    const int row0 = blockIdx.x * 64;

    for (int p = t; p < 8 * 136; p += 256) Wt2[40 + p / 136][p % 136] = 0;
    for (int p = t; p < 640; p += 256) {
        int n = p >> 4, k8 = (p & 15) * 8;
        *(uint4*)(&Wt2[n][k8]) = *(const uint4*)(w2t + n * 128 + k8);
    }
    {
        int r = t >> 2, c0 = (t & 3) * 32;
        int gr = row0 + r;
        if (gr < NODES) {
#pragma unroll
            for (int i = 0; i < 4; i++)
                *(uint4*)(&Asm[r][c0 + i * 8]) =
                    *(const uint4*)(out1b + (size_t)gr * C1 + c0 + i * 8);
        } else {
            uint4 z = make_uint4(0, 0, 0, 0);
#pragma unroll
            for (int i = 0; i < 4; i++) *(uint4*)(&Asm[r][c0 + i * 8]) = z;
        }
    }
    __syncthreads();

    const int w = t >> 6, l = t & 63;
    const int lm = l & 15, quad = l >> 4;
    f32x4 acc[3];
#pragma unroll
    for (int ct = 0; ct < 3; ct++) acc[ct] = (f32x4){0.f, 0.f, 0.f, 0.f};
#pragma unroll
    for (int kt = 0; kt < 4; kt++) {
        bf16x8 a = *(const bf16x8*)(&Asm[w * 16 + lm][kt * 32 + quad * 8]);
#pragma unroll
        for (int ct = 0; ct < 3; ct++) {
            bf16x8 b = *(const bf16x8*)(&Wt2[ct * 16 + lm][kt * 32 + quad * 8]);
            acc[ct] = __builtin_amdgcn_mfma_f32_16x16x32_bf16(a, b, acc[ct], 0, 0, 0);
        }
    }
    __syncthreads();
#pragma unroll
    for (int ct = 0; ct < 3; ct++)
#pragma unroll
        for (int r = 0; r < 4; r++)
            Cc[w * 16 + quad * 4 + r][ct * 16 + lm] = acc[ct][r];
    __syncthreads();
    {
        int r = t >> 2, c0 = (t & 3) * 10;
        int gr = row0 + r;
        if (gr < NODES) {
#pragma unroll
            for (int i = 0; i < 5; i++) {
                int c = c0 + i * 2;
                unsigned pk = cvtpk(Cc[r][c], Cc[r][c + 1]);
                *(unsigned*)(h2b + (size_t)gr * 40 + c) = pk;
            }
            float s = 0.f, d = 0.f;
#pragma unroll
            for (int j = 0; j < 10; j++) {
                float v = Cc[r][c0 + j];
                s = fmaf(v, AS[c0 + j], s);
                d = fmaf(v, AD[c0 + j], d);
            }
            s += __shfl_xor(s, 1); s += __shfl_xor(s, 2);
            d += __shfl_xor(d, 1); d += __shfl_xor(d, 2);
            if ((t & 3) == 0) { as2[gr] = s; ad2[gr] = d; }
        }
    }
}

// ---- layer-2 aggregation: one wave per dst node; adaptive 32/16 epochs;
//      h2b rows are 80 B (stride 40 ushorts). ----
__global__ __launch_bounds__(256) void k_agg2(const unsigned short* __restrict__ h2b,
                                              const float* __restrict__ as2,
                                              const float* __restrict__ ad2,
                                              const int* __restrict__ rowptr,
                                              const int* __restrict__ degarr,
                                              const int* __restrict__ col,
                                              const float* __restrict__ b2,
                                              float* __restrict__ out) {
    int wid = (blockIdx.x * 256 + threadIdx.x) >> 6;
    if (wid >= NODES) return;
    const int lane = threadIdx.x & 63;
    const int q8 = lane >> 3, l8 = lane & 7;
    const int n = wid;
    const float adn = ad2[n];
    const int rs = rowptr[n];
    const int re = rs + degarr[n];
    const unsigned lo = (unsigned)(l8 << 4);

    float den = 0.f;
    float ac[8];
#pragma unroll
    for (int k = 0; k < 8; k++) ac[k] = 0.f;

    int base = rs;
    for (; re - base > 16; base += 32) {
        // 32-wide: group q8 handles edges base+q8*4+{0..3}
        int4a cc = *(const int4a*)(col + base + q8 * 4);
        const int i0 = base + q8 * 4;
        int c0 = (i0 + 0 < re) ? cc.x : n;
        int c1 = (i0 + 1 < re) ? cc.y : n;
        int c2 = (i0 + 2 < re) ? cc.z : n;
        int c3 = (i0 + 3 < re) ? cc.w : n;
        float w0 = __expf(lrelu(as2[c0] + adn)); if (i0 + 0 >= re) w0 = 0.f;
        float w1 = __expf(lrelu(as2[c1] + adn)); if (i0 + 1 >= re) w1 = 0.f;
        float w2 = __expf(lrelu(as2[c2] + adn)); if (i0 + 2 >= re) w2 = 0.f;
        float w3 = __expf(lrelu(as2[c3] + adn)); if (i0 + 3 >= re) w3 = 0.f;
        den += (w0 + w1) + (w2 + w3);
        if (l8 < 5) {
            uint4 p0 = *(const uint4*)((const char*)h2b + ((unsigned)c0 * 80u + lo));
            uint4 p1 = *(const uint4*)((const char*)h2b + ((unsigned)c1 * 80u + lo));
            uint4 p2 = *(const uint4*)((const char*)h2b + ((unsigned)c2 * 80u + lo));
            uint4 p3 = *(const uint4*)((const char*)h2b + ((unsigned)c3 * 80u + lo));
            acc8(w0, p0, ac); acc8(w1, p1, ac);
            acc8(w2, p2, ac); acc8(w3, p3, ac);
        }
    }
    if (base < re) {
        // 16-wide: group q8 handles edges base+q8*2+{0,1}
        int2a cc = *(const int2a*)(col + base + q8 * 2);
        const int i0 = base + q8 * 2;
        int c0 = (i0 + 0 < re) ? cc.x : n;
        int c1 = (i0 + 1 < re) ? cc.y : n;
        float w0 = __expf(lrelu(as2[c0] + adn)); if (i0 + 0 >= re) w0 = 0.f;
        float w1 = __expf(lrelu(as2[c1] + adn)); if (i0 + 1 >= re) w1 = 0.f;
        den += w0 + w1;
        if (l8 < 5) {
            uint4 p0 = *(const uint4*)((const char*)h2b + ((unsigned)c0 * 80u + lo));
            uint4 p1 = *(const uint4*)((const char*)h2b + ((unsigned)c1 * 80u + lo));
            acc8(w0, p0, ac); acc8(w1, p1, ac);
        }
    }
    den += __shfl_xor(den, 8);
    den += __shfl_xor(den, 16);
    den += __shfl_xor(den, 32);
#pragma unroll
    for (int k = 0; k < 8; k++) {
        ac[k] += __shfl_xor(ac[k], 8);
        ac[k] += __shfl_xor(ac[k], 16);
        ac[k] += __shfl_xor(ac[k], 32);
    }
    const float wself = __expf(lrelu(as2[n] + adn));
    den += wself;
    if (q8 == 0 && l8 < 5) {
        unsigned offs = (unsigned)n * 80u + lo;
        uint4 sp = *(const uint4*)((const char*)h2b + offs);
        float sv[8] = {bflo(sp.x), bfhi(sp.x), bflo(sp.y), bfhi(sp.y),
                       bflo(sp.z), bfhi(sp.z), bflo(sp.w), bfhi(sp.w)};
        float4 bv0 = *(const float4*)(b2 + l8 * 8);
        float4 bv1 = *(const float4*)(b2 + l8 * 8 + 4);
        float bb[8] = {bv0.x, bv0.y, bv0.z, bv0.w, bv1.x, bv1.y, bv1.z, bv1.w};
        float o[8];
#pragma unroll
        for (int k = 0; k < 8; k++)
            o[k] = (ac[k] + wself * sv[k]) / den + bb[k];
        *(float4*)(out + (size_t)n * CLS + l8 * 8) =
            make_float4(o[0], o[1], o[2], o[3]);
        *(float4*)(out + (size_t)n * CLS + l8 * 8 + 4) =
            make_float4(o[4], o[5], o[6], o[7]);
    }
}

extern "C" void kernel_launch(void* const* d_in, const int* in_sizes, int n_in,
                              void* d_out, int out_size, void* d_ws, size_t ws_size,
                              hipStream_t stream) {
    const float* x     = (const float*)d_in[0];
    const int*   ei    = (const int*)d_in[1];
    const float* W1    = (const float*)d_in[2];
    const float* aS1   = (const float*)d_in[3];
    const float* aD1   = (const float*)d_in[4];
    const float* b1    = (const float*)d_in[5];
    const float* W2    = (const float*)d_in[6];
    const float* aS2   = (const float*)d_in[7];
    const float* aD2   = (const float*)d_in[8];
    const float* b2    = (const float*)d_in[9];
    float* out = (float*)d_out;
    const int E = in_sizes[1] / 2;
    const int* src = ei;
    const int* dst = ei + E;

    char* ws = (char*)d_ws;
    size_t off = 0;
    auto alloc = [&](size_t bytes) -> char* {
        char* p = ws + off;
        off += (bytes + 255) & ~(size_t)255;
        return p;
    };
    unsigned short* h1b  = (unsigned short*)alloc((size_t)NODES * C1 * 2);
    unsigned short* out1 = (unsigned short*)alloc((size_t)NODES * C1 * 2);
    unsigned short* h2b  = (unsigned short*)alloc((size_t)NODES * 40 * 2);
    float* as1    = (float*)alloc((size_t)NODES * HEADS * 4);
    float* ad1    = (float*)alloc((size_t)NODES * HEADS * 4);
    float* as2    = (float*)alloc((size_t)NODES * 4);
    float* ad2    = (float*)alloc((size_t)NODES * 4);
    int* rowptr   = (int*)alloc((size_t)NODES * 4);
    int* degarr   = (int*)alloc((size_t)NODES * 4);
    int* col      = (int*)alloc((size_t)NBUCK * BCAP * 4 + 1024);  // +slack for predicated reads
    int* tmp      = (int*)alloc((size_t)NBUCK * BCAP * 4 + 1024);
    unsigned short* w1t = (unsigned short*)alloc((size_t)FIN * C1 * 2);
    unsigned short* w2t = (unsigned short*)alloc((size_t)CLS * 128 * 2);
    int* bwp      = (int*)alloc((size_t)NBUCK * 4);

    const int GB1 = (NODES + 63) / 64;           // 782 gemm1 blocks
    const int GBA = (E + EPB - 1) / EPB;         // bucketA blocks

    k_prep<<<9, 256, 0, stream>>>(W1, W2, w1t, w2t, bwp);
    k_front<<<GB1 + GBA, 256, 0, stream>>>(x, w1t, aS1, aD1, h1b, as1, ad1,
                                           src, dst, E, bwp, tmp, GB1);
    k_bucketB<<<NBUCK, 512, 0, stream>>>(bwp, tmp, col, rowptr, degarr);
    k_agg1<<<(NODES * 64) / 256, 256, 0, stream>>>(h1b, as1, ad1, rowptr, degarr,
                                                   col, b1, out1);
    k_gemm2<<<(NODES + 63) / 64, 256, 0, stream>>>(out1, w2t, aS2, aD2, h2b, as2, ad2);
    k_agg2<<<(NODES * 64) / 256, 256, 0, stream>>>(h2b, as2, ad2, rowptr, degarr,
                                                   col, b2, out);
}